// Round 9
// baseline (1747.161 us; speedup 1.0000x reference)
//
#include <hip/hip_runtime.h>

#define N_ITEMS 20000
#define N_USERS 2048
#define NNZ     4000000
#define LDP     2112   // padded XT leading dim (66 cache lines: breaks L2/L3 set aliasing)
#define CAP     320    // per-row bucket capacity; rows ~Poisson(200), P(any row >320) ~ 1e-13

typedef float    f32x4 __attribute__((ext_vector_type(4)));
typedef unsigned u32x2 __attribute__((ext_vector_type(2)));

// ---------------- ws layout (bytes) ----------------
#define OFF_XT     ((size_t)0)                    // bf16 [20000][2112] = 84,480,000
#define OFF_CSRPK  ((size_t)84480000)             // u32 [20000*320]   = 25,600,000
#define OFF_CNT    (OFF_CSRPK + 25600000)         // int [20000]

static __device__ __forceinline__ unsigned short f2bf(float f) {
  unsigned u = __float_as_uint(f);
  unsigned r = (u + 0x7fffu + ((u >> 16) & 1u)) >> 16;
  return (unsigned short)r;
}

#define NT_BLOCKS (313 * 32)                 // transpose tiles (313 k-tiles x 32 u-tiles)
#define NS_BLOCKS ((NNZ / 4 + 255) / 256)    // scatter blocks (4 nnz/thread)

// Fused: transpose X -> XT (bf16, padded) in blocks [0, NT_BLOCKS);
//        COO -> fixed-capacity row buckets in blocks [NT_BLOCKS, +NS_BLOCKS).
// Independent inputs/outputs -> safe to run concurrently in one dispatch.
__global__ __launch_bounds__(256) void prep_kernel(
    const float* __restrict__ X, const float* __restrict__ vals,
    const int* __restrict__ rows, const int* __restrict__ cols,
    unsigned short* __restrict__ XT, int* __restrict__ cnt,
    unsigned* __restrict__ csr_pk) {
  int b = blockIdx.x;
  if (b < NT_BLOCKS) {
    __shared__ float tile[64][65];
    int k0 = (b % 313) * 64;
    int u0 = (b / 313) * 64;
    int lane = threadIdx.x & 63;
    int dq = threadIdx.x >> 6;
    #pragma unroll
    for (int m = 0; m < 16; ++m) {
      int u = u0 + dq + 4 * m;
      int k = k0 + lane;
      float v = 0.f;
      if (k < N_ITEMS) v = X[(size_t)u * N_ITEMS + k];
      tile[lane][dq + 4 * m] = v;
    }
    __syncthreads();
    #pragma unroll
    for (int m = 0; m < 16; ++m) {
      int k = k0 + dq + 4 * m;
      if (k < N_ITEMS)
        XT[(size_t)k * LDP + u0 + lane] = f2bf(tile[dq + 4 * m][lane]);
    }
  } else {
    int i = ((b - NT_BLOCKS) * 256 + threadIdx.x) * 4;
    if (i < NNZ) {  // NNZ % 4 == 0: quads always complete
      int4   r4 = *reinterpret_cast<const int4*>(rows + i);
      int4   c4 = *reinterpret_cast<const int4*>(cols + i);
      float4 v4 = *reinterpret_cast<const float4*>(vals + i);
      #pragma unroll
      for (int k = 0; k < 4; ++k) {
        int   r = (k == 0) ? r4.x : (k == 1) ? r4.y : (k == 2) ? r4.z : r4.w;
        int   c = (k == 0) ? c4.x : (k == 1) ? c4.y : (k == 2) ? c4.z : c4.w;
        float v = (k == 0) ? v4.x : (k == 1) ? v4.y : (k == 2) ? v4.z : v4.w;
        int pos = atomicAdd(&cnt[r], 1);
        if (pos >= CAP) pos = CAP - 1;  // astronomically unlikely; keep in-bounds
        csr_pk[r * CAP + pos] = (unsigned)c | ((unsigned)f2bf(v) << 16);
      }
    }
  }
}

// Out[u,r] = sum_j val(j) * XT[col(j)][u]
// WG: 256 thr = 4 waves; 16 rows x 256 users (4 users/lane, dwordx2 gathers).
// grid = 1250 rb x 8 uchunks; xcd = wg&7 = uchunk (one 256-user slice per XCD).
// Row entries are wave-uniform -> csr loads scalarize (s_load, lgkmcnt) and
// vals live in SGPRs; gathers (vmcnt) are software-pipelined 2 batches deep:
// gathers for batch b+1 are issued before the FMAs of batch b.
__global__ __launch_bounds__(256) void spmm_kernel(
    const int* __restrict__ cnt, const unsigned* __restrict__ csr_pk,
    const unsigned short* __restrict__ xt, float* __restrict__ out) {
  __shared__ float tile[16][264];
  int wg = blockIdx.x;
  int xcd = wg & 7;
  int rb  = wg >> 3;   // [0, 1250)
  int u0 = xcd * 256;
  int r0 = rb * 16;
  int lane = threadIdx.x & 63;
  int wave = __builtin_amdgcn_readfirstlane((int)(threadIdx.x >> 6));
  const unsigned short* xt_u = xt + u0 + 4 * lane;

#define LOAD8(E, BASE)                                                   \
  { _Pragma("unroll")                                                    \
    for (int k = 0; k < 8; ++k) E[k] = csr_pk[(BASE) + k]; }
#define GATHER8(G, E)                                                    \
  { _Pragma("unroll")                                                    \
    for (int k = 0; k < 8; ++k)                                          \
      G[k] = *reinterpret_cast<const u32x2*>(xt_u + (E[k] & 0x7fffu) * LDP); }
#define EXTRACT8(V, E)                                                   \
  { _Pragma("unroll")                                                    \
    for (int k = 0; k < 8; ++k) V[k] = __uint_as_float(E[k] & 0xffff0000u); }
#define FMA8(G, V)                                                       \
  { _Pragma("unroll")                                                    \
    for (int k = 0; k < 8; ++k) {                                        \
      a0 = fmaf(V[k], __uint_as_float(G[k].x << 16), a0);                \
      a1 = fmaf(V[k], __uint_as_float(G[k].x & 0xffff0000u), a1);        \
      a2 = fmaf(V[k], __uint_as_float(G[k].y << 16), a2);                \
      a3 = fmaf(V[k], __uint_as_float(G[k].y & 0xffff0000u), a3);        \
    } }

  #pragma unroll 1
  for (int rr = 0; rr < 4; ++rr) {
    int r = r0 + wave * 4 + rr;
    int jb = r * CAP;
    int cr = __builtin_amdgcn_readfirstlane(cnt[r]);
    if (cr > CAP) cr = CAP;
    int je = jb + cr;
    float a0 = 0.f, a1 = 0.f, a2 = 0.f, a3 = 0.f;
    int nb = cr >> 3;
    int j = jb;
    if (nb >= 2) {
      unsigned e0[8], e1[8];
      u32x2 g0[8], g1[8];
      float v[8];
      LOAD8(e0, jb)
      GATHER8(g0, e0)
      LOAD8(e1, jb + 8)
      int b = 0;
      for (; b + 3 < nb; b += 2) {
        // even: compute batch b, prefetch b+2
        GATHER8(g1, e1)
        EXTRACT8(v, e0)
        LOAD8(e0, jb + (b + 2) * 8)
        FMA8(g0, v)
        // odd: compute batch b+1, prefetch b+3
        GATHER8(g0, e0)
        EXTRACT8(v, e1)
        LOAD8(e1, jb + (b + 3) * 8)
        FMA8(g1, v)
      }
      // invariant: g0=gathers(b), e0=entries(b), e1=entries(b+1); rem in {2,3}
      GATHER8(g1, e1)
      EXTRACT8(v, e0)
      FMA8(g0, v)
      if (nb - b == 3) {
        LOAD8(e0, jb + (b + 2) * 8)
        GATHER8(g0, e0)
        EXTRACT8(v, e1)
        FMA8(g1, v)
        EXTRACT8(v, e0)
        FMA8(g0, v)
      } else {
        EXTRACT8(v, e1)
        FMA8(g1, v)
      }
      j = jb + nb * 8;
    } else if (nb == 1) {
      unsigned e0[8]; u32x2 g0[8]; float v[8];
      LOAD8(e0, jb)
      GATHER8(g0, e0)
      EXTRACT8(v, e0)
      FMA8(g0, v)
      j = jb + 8;
    }
    for (; j < je; ++j) {
      unsigned ee = csr_pk[j];
      u32x2 g = *reinterpret_cast<const u32x2*>(xt_u + (ee & 0x7fffu) * LDP);
      float vv = __uint_as_float(ee & 0xffff0000u);
      a0 = fmaf(vv, __uint_as_float(g.x << 16), a0);
      a1 = fmaf(vv, __uint_as_float(g.x & 0xffff0000u), a1);
      a2 = fmaf(vv, __uint_as_float(g.y << 16), a2);
      a3 = fmaf(vv, __uint_as_float(g.y & 0xffff0000u), a3);
    }
    f32x4 o; o.x = a0; o.y = a1; o.z = a2; o.w = a3;
    *reinterpret_cast<f32x4*>(&tile[wave * 4 + rr][4 * lane]) = o;
  }
#undef LOAD8
#undef GATHER8
#undef EXTRACT8
#undef FMA8

  __syncthreads();
  // store: thread t = user t; 16 contiguous r's = 64 B, 4x f32x4 NT stores
  int ul = threadIdx.x;
  float* op = &out[(size_t)(u0 + ul) * N_ITEMS + r0];
  f32x4 s0, s1, s2, s3;
  s0.x = tile[ 0][ul]; s0.y = tile[ 1][ul]; s0.z = tile[ 2][ul]; s0.w = tile[ 3][ul];
  s1.x = tile[ 4][ul]; s1.y = tile[ 5][ul]; s1.z = tile[ 6][ul]; s1.w = tile[ 7][ul];
  s2.x = tile[ 8][ul]; s2.y = tile[ 9][ul]; s2.z = tile[10][ul]; s2.w = tile[11][ul];
  s3.x = tile[12][ul]; s3.y = tile[13][ul]; s3.z = tile[14][ul]; s3.w = tile[15][ul];
  __builtin_nontemporal_store(s0, reinterpret_cast<f32x4*>(op) + 0);
  __builtin_nontemporal_store(s1, reinterpret_cast<f32x4*>(op) + 1);
  __builtin_nontemporal_store(s2, reinterpret_cast<f32x4*>(op) + 2);
  __builtin_nontemporal_store(s3, reinterpret_cast<f32x4*>(op) + 3);
}

extern "C" void kernel_launch(void* const* d_in, const int* in_sizes, int n_in,
                              void* d_out, int out_size, void* d_ws, size_t ws_size,
                              hipStream_t stream) {
  const float* X      = (const float*)d_in[0];
  const float* S_vals = (const float*)d_in[1];
  const int*   S_rows = (const int*)d_in[2];
  const int*   S_cols = (const int*)d_in[3];
  float* out = (float*)d_out;

  char* ws = (char*)d_ws;
  unsigned short* XT = (unsigned short*)(ws + OFF_XT);
  unsigned* csr_pk   = (unsigned*)(ws + OFF_CSRPK);
  int* cnt           = (int*)(ws + OFF_CNT);

  hipMemsetAsync(cnt, 0, N_ITEMS * sizeof(int), stream);
  prep_kernel<<<NT_BLOCKS + NS_BLOCKS, 256, 0, stream>>>(
      X, S_vals, S_rows, S_cols, XT, cnt, csr_pk);
  spmm_kernel<<<1250 * 8, 256, 0, stream>>>(cnt, csr_pk, XT, out);
}

// Round 10
// 1072.940 us; speedup vs baseline: 1.6284x; 1.6284x over previous
//
#include <hip/hip_runtime.h>

#define N_ITEMS 20000
#define N_USERS 2048
#define NNZ     4000000
#define LDP     2112   // padded XT leading dim (66 cache lines: breaks L2/L3 set aliasing)
#define CAP     320    // per-row bucket capacity; rows ~Poisson(200), max est ~263

typedef float f32x4 __attribute__((ext_vector_type(4)));

// ---------------- ws layout (bytes) ----------------
#define OFF_XT     ((size_t)0)                    // bf16 [20000][2112] = 84,480,000
#define OFF_CSROFF ((size_t)84480000)             // u32 [20000*320] byte-offsets = 25,600,000
#define OFF_CSRVAL (OFF_CSROFF + 25600000)        // u16 [20000*320] bf16 vals    = 12,800,000
#define OFF_CNT    (OFF_CSRVAL + 12800000)        // int [20000]
// total ~123 MB (R3 used 126.3 MB successfully)

static __device__ __forceinline__ unsigned short f2bf(float f) {
  unsigned u = __float_as_uint(f);
  unsigned r = (u + 0x7fffu + ((u >> 16) & 1u)) >> 16;
  return (unsigned short)r;
}

#define NT_BLOCKS (313 * 32)                 // transpose tiles
#define NS_BLOCKS ((NNZ / 4 + 255) / 256)    // scatter blocks (4 nnz/thread)

// Fused: transpose X -> XT (bf16, padded) + COO -> fixed-capacity row buckets.
__global__ __launch_bounds__(256) void prep_kernel(
    const float* __restrict__ X, const float* __restrict__ vals,
    const int* __restrict__ rows, const int* __restrict__ cols,
    unsigned short* __restrict__ XT, int* __restrict__ cnt,
    unsigned* __restrict__ csr_off, unsigned short* __restrict__ csr_val) {
  int b = blockIdx.x;
  if (b < NT_BLOCKS) {
    __shared__ float tile[64][65];
    int k0 = (b % 313) * 64;
    int u0 = (b / 313) * 64;
    int lane = threadIdx.x & 63;
    int dq = threadIdx.x >> 6;
    #pragma unroll
    for (int m = 0; m < 16; ++m) {
      int u = u0 + dq + 4 * m;
      int k = k0 + lane;
      float v = 0.f;
      if (k < N_ITEMS) v = X[(size_t)u * N_ITEMS + k];
      tile[lane][dq + 4 * m] = v;
    }
    __syncthreads();
    #pragma unroll
    for (int m = 0; m < 16; ++m) {
      int k = k0 + dq + 4 * m;
      if (k < N_ITEMS)
        XT[(size_t)k * LDP + u0 + lane] = f2bf(tile[dq + 4 * m][lane]);
    }
  } else {
    int i = ((b - NT_BLOCKS) * 256 + threadIdx.x) * 4;
    if (i < NNZ) {  // NNZ % 4 == 0: quads always complete
      int4   r4 = *reinterpret_cast<const int4*>(rows + i);
      int4   c4 = *reinterpret_cast<const int4*>(cols + i);
      float4 v4 = *reinterpret_cast<const float4*>(vals + i);
      #pragma unroll
      for (int k = 0; k < 4; ++k) {
        int   r = (k == 0) ? r4.x : (k == 1) ? r4.y : (k == 2) ? r4.z : r4.w;
        int   c = (k == 0) ? c4.x : (k == 1) ? c4.y : (k == 2) ? c4.z : c4.w;
        float v = (k == 0) ? v4.x : (k == 1) ? v4.y : (k == 2) ? v4.z : v4.w;
        int pos = atomicAdd(&cnt[r], 1);
        if (pos >= CAP) pos = CAP - 1;  // astronomically unlikely; stay in-bounds
        csr_off[r * CAP + pos] = (unsigned)c * (LDP * 2);  // precomputed BYTE offset
        csr_val[r * CAP + pos] = f2bf(v);
      }
    }
  }
}

// Out[u,r] = sum_j val(j) * XT[col(j)][u]
// WG: 256 thr = 4 waves; 16 rows x 128 users (2 users/lane, dword gathers).
// grid = 1250 rb * 16 uchunks; xcd = wg&7 owns uchunks {2x,2x+1} (5.12 MB slice,
// ~14% L2 miss absorbed by L3 -- accepted; R9 proved bigger slices are worse).
// KEY: row entries are wave-uniform -> s_load into SGPRs; gather address =
// SGPR base (xt + u0 + s_off, scalar adds) + constant VGPR (4*lane) -> ZERO
// VALU address arithmetic. Inner loop VALU = 2 extracts + 2 FMAs per dword.
__global__ __launch_bounds__(256) void spmm_kernel(
    const int* __restrict__ cnt, const unsigned* __restrict__ csr_off,
    const unsigned short* __restrict__ csr_val,
    const unsigned short* __restrict__ xt, float* __restrict__ out) {
  __shared__ float tile[16][132];
  int wg = blockIdx.x;
  int xcd = wg & 7;
  int slot = wg >> 3;            // [0, 2500)
  int combo = slot / 1250;       // 0..1
  int rb = slot - combo * 1250;  // [0, 1250)
  int uchunk = xcd * 2 + combo;
  int u0 = uchunk * 128;
  int r0 = rb * 16;
  int lane = threadIdx.x & 63;
  int wave = __builtin_amdgcn_readfirstlane((int)(threadIdx.x >> 6));
  const char* xtb = (const char*)xt + (size_t)u0 * 2;  // wave-uniform base
  int lane4 = 4 * lane;                                // constant per-lane voffset

  // O[k]: uniform byte offsets (SGPR); V[k]: uniform f32-bit vals (SGPR).
#define SLOAD8(O, V, B8)                                                     \
  { _Pragma("unroll")                                                        \
    for (int k = 0; k < 8; ++k)                                              \
      O[k] = __builtin_amdgcn_readfirstlane((int)offp[(B8) + k]);            \
    _Pragma("unroll")                                                        \
    for (int k = 0; k < 4; ++k) {                                            \
      unsigned d = (unsigned)__builtin_amdgcn_readfirstlane(                 \
          (int)valp32[((B8) >> 1) + k]);                                     \
      V[2 * k]     = d << 16;                                                \
      V[2 * k + 1] = d & 0xffff0000u;                                        \
    } }
#define GATHER8(G, O)                                                        \
  { _Pragma("unroll")                                                        \
    for (int k = 0; k < 8; ++k)                                              \
      G[k] = *reinterpret_cast<const unsigned*>(xtb + O[k] + lane4); }
#define FMA8(G, V)                                                           \
  { _Pragma("unroll")                                                        \
    for (int k = 0; k < 8; ++k) {                                            \
      float vv = __uint_as_float(V[k]);                                      \
      float xl = __uint_as_float(G[k] << 16);                                \
      float xh = __uint_as_float(G[k] & 0xffff0000u);                        \
      if (k & 1) { a2 = fmaf(vv, xl, a2); a3 = fmaf(vv, xh, a3); }           \
      else       { a0 = fmaf(vv, xl, a0); a1 = fmaf(vv, xh, a1); }           \
    } }

  #pragma unroll 1
  for (int rr = 0; rr < 4; ++rr) {
    int r = r0 + wave * 4 + rr;
    int jb = __builtin_amdgcn_readfirstlane(r * CAP);
    int cr = __builtin_amdgcn_readfirstlane(cnt[r]);
    if (cr > CAP) cr = CAP;
    const unsigned* offp = csr_off + jb;                    // uniform
    const unsigned* valp32 = (const unsigned*)(csr_val + jb);  // jb even (CAP=320)
    float a0 = 0.f, a1 = 0.f, a2 = 0.f, a3 = 0.f;
    int nb = cr >> 3;
    if (nb >= 2) {
      int o0[8], o1[8];
      unsigned v0[8], v1[8], g0[8], g1[8];
      SLOAD8(o0, v0, 0)
      GATHER8(g0, o0)
      SLOAD8(o1, v1, 8)
      int b = 0;
      for (; b + 3 < nb; b += 2) {
        GATHER8(g1, o1)              // issue gathers b+1
        FMA8(g0, v0)                 // compute b
        SLOAD8(o0, v0, (b + 2) * 8)  // prefetch entries b+2
        GATHER8(g0, o0)              // issue gathers b+2
        FMA8(g1, v1)                 // compute b+1
        SLOAD8(o1, v1, (b + 3) * 8)  // prefetch entries b+3
      }
      // invariant: g0=gathers(b), v0=vals(b), o1/v1=entries(b+1); rem in {2,3}
      GATHER8(g1, o1)
      FMA8(g0, v0)
      if (nb - b == 3) {
        SLOAD8(o0, v0, (b + 2) * 8)
        GATHER8(g0, o0)
        FMA8(g1, v1)
        FMA8(g0, v0)
      } else {
        FMA8(g1, v1)
      }
    } else if (nb == 1) {
      int o0[8]; unsigned v0[8], g0[8];
      SLOAD8(o0, v0, 0)
      GATHER8(g0, o0)
      FMA8(g0, v0)
    }
    for (int j = nb * 8; j < cr; ++j) {
      int o = __builtin_amdgcn_readfirstlane((int)offp[j]);
      unsigned vv = (unsigned)__builtin_amdgcn_readfirstlane((int)csr_val[jb + j]);
      unsigned g = *reinterpret_cast<const unsigned*>(xtb + o + lane4);
      float vf = __uint_as_float(vv << 16);
      a0 = fmaf(vf, __uint_as_float(g << 16), a0);
      a1 = fmaf(vf, __uint_as_float(g & 0xffff0000u), a1);
    }
    tile[wave * 4 + rr][2 * lane]     = a0 + a2;  // user u0 + 2*lane
    tile[wave * 4 + rr][2 * lane + 1] = a1 + a3;  // user u0 + 2*lane + 1
  }
#undef SLOAD8
#undef GATHER8
#undef FMA8

  __syncthreads();
  // store [128u x 16r]; thread t -> (ul = t>>1, rseg = (t&1)*8), 2x f32x4 NT
  int ul = threadIdx.x >> 1;
  int rseg = (threadIdx.x & 1) * 8;
  float* op = &out[(size_t)(u0 + ul) * N_ITEMS + r0 + rseg];
  f32x4 o0, o1;
  o0.x = tile[rseg + 0][ul]; o0.y = tile[rseg + 1][ul];
  o0.z = tile[rseg + 2][ul]; o0.w = tile[rseg + 3][ul];
  o1.x = tile[rseg + 4][ul]; o1.y = tile[rseg + 5][ul];
  o1.z = tile[rseg + 6][ul]; o1.w = tile[rseg + 7][ul];
  __builtin_nontemporal_store(o0, reinterpret_cast<f32x4*>(op));
  __builtin_nontemporal_store(o1, reinterpret_cast<f32x4*>(op) + 1);
}

extern "C" void kernel_launch(void* const* d_in, const int* in_sizes, int n_in,
                              void* d_out, int out_size, void* d_ws, size_t ws_size,
                              hipStream_t stream) {
  const float* X      = (const float*)d_in[0];
  const float* S_vals = (const float*)d_in[1];
  const int*   S_rows = (const int*)d_in[2];
  const int*   S_cols = (const int*)d_in[3];
  float* out = (float*)d_out;

  char* ws = (char*)d_ws;
  unsigned short* XT       = (unsigned short*)(ws + OFF_XT);
  unsigned* csr_off        = (unsigned*)(ws + OFF_CSROFF);
  unsigned short* csr_val  = (unsigned short*)(ws + OFF_CSRVAL);
  int* cnt                 = (int*)(ws + OFF_CNT);

  hipMemsetAsync(cnt, 0, N_ITEMS * sizeof(int), stream);
  prep_kernel<<<NT_BLOCKS + NS_BLOCKS, 256, 0, stream>>>(
      X, S_vals, S_rows, S_cols, XT, cnt, csr_off, csr_val);
  spmm_kernel<<<1250 * 16, 256, 0, stream>>>(cnt, csr_off, csr_val, XT, out);
}

// Round 11
// 1039.002 us; speedup vs baseline: 1.6816x; 1.0327x over previous
//
#include <hip/hip_runtime.h>

#define N_ITEMS 20000
#define N_USERS 2048
#define NNZ     4000000
#define LDP     2112   // padded XT leading dim (66 cache lines: breaks L2/L3 set aliasing)
#define CAP     320    // per-row bucket capacity; rows ~Poisson(200), P(overflow) ~ 1e-13

typedef float f32x4 __attribute__((ext_vector_type(4)));

// ---------------- ws layout (bytes) ----------------
#define OFF_XT     ((size_t)0)                    // bf16 [20000][2112] = 84,480,000
#define OFF_CSRPK  ((size_t)84480000)             // u32 [20000*320] (bf16val<<16 | col) = 25,600,000
#define OFF_CNT    (OFF_CSRPK + 25600000)         // int [20000]

static __device__ __forceinline__ unsigned short f2bf(float f) {
  unsigned u = __float_as_uint(f);
  unsigned r = (u + 0x7fffu + ((u >> 16) & 1u)) >> 16;
  return (unsigned short)r;
}

#define NT_BLOCKS (313 * 32)                 // transpose tiles
#define NS_BLOCKS ((NNZ / 4 + 255) / 256)    // scatter blocks (4 nnz/thread)

// Fused: transpose X -> XT (bf16, padded) + COO -> fixed-capacity row buckets.
// csr_pk entry = (bf16(val) << 16) | col   (col < 32768 fits 15 bits)
__global__ __launch_bounds__(256) void prep_kernel(
    const float* __restrict__ X, const float* __restrict__ vals,
    const int* __restrict__ rows, const int* __restrict__ cols,
    unsigned short* __restrict__ XT, int* __restrict__ cnt,
    unsigned* __restrict__ csr_pk) {
  int b = blockIdx.x;
  if (b < NT_BLOCKS) {
    __shared__ float tile[64][65];
    int k0 = (b % 313) * 64;
    int u0 = (b / 313) * 64;
    int lane = threadIdx.x & 63;
    int dq = threadIdx.x >> 6;
    #pragma unroll
    for (int m = 0; m < 16; ++m) {
      int u = u0 + dq + 4 * m;
      int k = k0 + lane;
      float v = 0.f;
      if (k < N_ITEMS) v = X[(size_t)u * N_ITEMS + k];
      tile[lane][dq + 4 * m] = v;
    }
    __syncthreads();
    #pragma unroll
    for (int m = 0; m < 16; ++m) {
      int k = k0 + dq + 4 * m;
      if (k < N_ITEMS)
        XT[(size_t)k * LDP + u0 + lane] = f2bf(tile[dq + 4 * m][lane]);
    }
  } else {
    int i = ((b - NT_BLOCKS) * 256 + threadIdx.x) * 4;
    if (i < NNZ) {  // NNZ % 4 == 0: quads always complete
      int4   r4 = *reinterpret_cast<const int4*>(rows + i);
      int4   c4 = *reinterpret_cast<const int4*>(cols + i);
      float4 v4 = *reinterpret_cast<const float4*>(vals + i);
      #pragma unroll
      for (int k = 0; k < 4; ++k) {
        int   r = (k == 0) ? r4.x : (k == 1) ? r4.y : (k == 2) ? r4.z : r4.w;
        int   c = (k == 0) ? c4.x : (k == 1) ? c4.y : (k == 2) ? c4.z : c4.w;
        float v = (k == 0) ? v4.x : (k == 1) ? v4.y : (k == 2) ? v4.z : v4.w;
        int pos = atomicAdd(&cnt[r], 1);
        if (pos >= CAP) pos = CAP - 1;  // astronomically unlikely; stay in-bounds
        csr_pk[r * CAP + pos] = ((unsigned)f2bf(v) << 16) | (unsigned)c;
      }
    }
  }
}

// Out[u,r] = sum_j val(j) * XT[col(j)][u]
// WG: 256 thr = 4 waves; 16 rows x 128 users (2 users/lane, dword gathers).
// grid = 1250 rb * 16 uchunks; xcd = wg&7 owns uchunks {2x,2x+1}.
// VALU trim: val = bits(e) DIRECT (col bits are mantissa noise ~2^-9 rel);
// hi-user x = bits(g) DIRECT (lo-user bits are mantissa noise); only the
// lo-user extract needs a shift. ~4 VALU per dword-gather.
// Buckets zero-padded to multiples of 8 (memset) -> no tail loop at all.
__global__ __launch_bounds__(256) void spmm_kernel(
    const int* __restrict__ cnt, const unsigned* __restrict__ csr_pk,
    const unsigned short* __restrict__ xt, float* __restrict__ out) {
  __shared__ float tile[16][132];
  int wg = blockIdx.x;
  int xcd = wg & 7;
  int slot = wg >> 3;            // [0, 2500)
  int combo = slot / 1250;       // 0..1
  int rb = slot - combo * 1250;  // [0, 1250)
  int uchunk = xcd * 2 + combo;
  int u0 = uchunk * 128;
  int r0 = rb * 16;
  int lane = threadIdx.x & 63;
  int wave = __builtin_amdgcn_readfirstlane((int)(threadIdx.x >> 6));
  const char* xtb = (const char*)(xt + u0) + 4 * lane;  // base + per-lane voffset

#define LOAD8(E, BASE)                                                   \
  { _Pragma("unroll")                                                    \
    for (int k = 0; k < 8; ++k) E[k] = csr_pk[(BASE) + k]; }
#define GATHER8(G, E)                                                    \
  { _Pragma("unroll")                                                    \
    for (int k = 0; k < 8; ++k)                                          \
      G[k] = *reinterpret_cast<const unsigned*>(                         \
          xtb + (E[k] & 0xffffu) * (LDP * 2)); }
#define FMA8(G, E)                                                       \
  { _Pragma("unroll")                                                    \
    for (int k = 0; k < 8; ++k) {                                        \
      float v  = __uint_as_float(E[k]);          /* col bits = noise */  \
      float xl = __uint_as_float(G[k] << 16);                            \
      float xh = __uint_as_float(G[k]);          /* lo bits = noise  */  \
      if (k & 1) { a2 = fmaf(v, xl, a2); a3 = fmaf(v, xh, a3); }         \
      else       { a0 = fmaf(v, xl, a0); a1 = fmaf(v, xh, a1); }         \
    } }

  #pragma unroll 1
  for (int rr = 0; rr < 4; ++rr) {
    int r = r0 + wave * 4 + rr;
    int jb = r * CAP;
    int cr = __builtin_amdgcn_readfirstlane(cnt[r]);
    if (cr > CAP) cr = CAP;
    int nb = (cr + 7) >> 3;  // buckets zero-padded: no tail handling
    float a0 = 0.f, a1 = 0.f, a2 = 0.f, a3 = 0.f;
    if (nb >= 2) {
      unsigned e0[8], e1[8], g0[8], g1[8];
      LOAD8(e0, jb)
      GATHER8(g0, e0)
      LOAD8(e1, jb + 8)
      int b = 0;
      for (; b + 3 < nb; b += 2) {
        GATHER8(g1, e1)              // issue gathers b+1
        FMA8(g0, e0)                 // compute b
        LOAD8(e0, jb + (b + 2) * 8)  // prefetch entries b+2
        GATHER8(g0, e0)              // issue gathers b+2
        FMA8(g1, e1)                 // compute b+1
        LOAD8(e1, jb + (b + 3) * 8)  // prefetch entries b+3
      }
      // invariant: g0=gathers(b), e0=entries(b), e1=entries(b+1); rem in {2,3}
      GATHER8(g1, e1)
      FMA8(g0, e0)
      if (nb - b == 3) {
        LOAD8(e0, jb + (b + 2) * 8)
        GATHER8(g0, e0)
        FMA8(g1, e1)
        FMA8(g0, e0)
      } else {
        FMA8(g1, e1)
      }
    } else if (nb == 1) {
      unsigned e0[8], g0[8];
      LOAD8(e0, jb)
      GATHER8(g0, e0)
      FMA8(g0, e0)
    }
    tile[wave * 4 + rr][2 * lane]     = a0 + a2;  // user u0 + 2*lane
    tile[wave * 4 + rr][2 * lane + 1] = a1 + a3;  // user u0 + 2*lane + 1
  }
#undef LOAD8
#undef GATHER8
#undef FMA8

  __syncthreads();
  // store [128u x 16r]; thread t -> (ul = t>>1, rseg = (t&1)*8), 2x f32x4 NT
  int ul = threadIdx.x >> 1;
  int rseg = (threadIdx.x & 1) * 8;
  float* op = &out[(size_t)(u0 + ul) * N_ITEMS + r0 + rseg];
  f32x4 o0, o1;
  o0.x = tile[rseg + 0][ul]; o0.y = tile[rseg + 1][ul];
  o0.z = tile[rseg + 2][ul]; o0.w = tile[rseg + 3][ul];
  o1.x = tile[rseg + 4][ul]; o1.y = tile[rseg + 5][ul];
  o1.z = tile[rseg + 6][ul]; o1.w = tile[rseg + 7][ul];
  __builtin_nontemporal_store(o0, reinterpret_cast<f32x4*>(op));
  __builtin_nontemporal_store(o1, reinterpret_cast<f32x4*>(op) + 1);
}

extern "C" void kernel_launch(void* const* d_in, const int* in_sizes, int n_in,
                              void* d_out, int out_size, void* d_ws, size_t ws_size,
                              hipStream_t stream) {
  const float* X      = (const float*)d_in[0];
  const float* S_vals = (const float*)d_in[1];
  const int*   S_rows = (const int*)d_in[2];
  const int*   S_cols = (const int*)d_in[3];
  float* out = (float*)d_out;

  char* ws = (char*)d_ws;
  unsigned short* XT = (unsigned short*)(ws + OFF_XT);
  unsigned* csr_pk   = (unsigned*)(ws + OFF_CSRPK);
  int* cnt           = (int*)(ws + OFF_CNT);

  hipMemsetAsync(cnt, 0, N_ITEMS * sizeof(int), stream);
  hipMemsetAsync(csr_pk, 0, (size_t)N_ITEMS * CAP * sizeof(unsigned), stream);
  prep_kernel<<<NT_BLOCKS + NS_BLOCKS, 256, 0, stream>>>(
      X, S_vals, S_rows, S_cols, XT, cnt, csr_pk);
  spmm_kernel<<<1250 * 16, 256, 0, stream>>>(cnt, csr_pk, XT, out);
}